// Round 1
// baseline (148.584 us; speedup 1.0000x reference)
//
#include <hip/hip_runtime.h>
#include <hip/hip_bf16.h>
#include <stdint.h>

// GPTQ 4-bit fused dequant + GEMM.  x[128,4096]f32 @ W[4096,11008] -> out[128,11008]f32
// W[k][n] = scales[k/128][n] * nibble(qweight[k/8][n], k%8) - zeros[k/128][n]
//
// R1: bf16 MFMA 16x16x32, BM=128 BN=64 BK=64, 4 waves (each 64x32),
//     XOR-swizzled LDS (conflict-free ds_read_b128), reg-staged, single-buffered.

#define IN_F   4096
#define OUT_F  11008
#define BATCH  128
#define BK     64
#define BN     64
#define NCHUNK (IN_F / BK)   // 64

typedef __attribute__((ext_vector_type(8))) short short8;
typedef __attribute__((ext_vector_type(4))) float f32x4;

static __device__ __forceinline__ unsigned int f2bf_pack(float lo, float hi) {
  // round-to-nearest-even bf16 pair packed into one u32
  unsigned int a = __float_as_uint(lo);
  unsigned int b = __float_as_uint(hi);
  a += 0x7FFFu + ((a >> 16) & 1u);
  b += 0x7FFFu + ((b >> 16) & 1u);
  return (a >> 16) | (b & 0xFFFF0000u);
}

__global__ __launch_bounds__(256) void cvt_kernel(const float* __restrict__ x,
                                                  unsigned int* __restrict__ xb) {
  int i = blockIdx.x * 256 + threadIdx.x;   // 8 floats -> 4 u32 (8 bf16) per thread
  float4 v0 = *(const float4*)(x + (size_t)i * 8);
  float4 v1 = *(const float4*)(x + (size_t)i * 8 + 4);
  uint4 o;
  o.x = f2bf_pack(v0.x, v0.y);
  o.y = f2bf_pack(v0.z, v0.w);
  o.z = f2bf_pack(v1.x, v1.y);
  o.w = f2bf_pack(v1.z, v1.w);
  *(uint4*)(xb + (size_t)i * 4) = o;
}

__global__ __launch_bounds__(256) void gptq_gemm(
    const unsigned short* __restrict__ xb,  // [128,4096] bf16 (may be null)
    const float* __restrict__ x,            // [128,4096] f32 fallback
    const int* __restrict__ qweight,        // [512, 11008]
    const float* __restrict__ scales,       // [32, 11008]
    const float* __restrict__ zeros,        // [32, 11008]
    float* __restrict__ out,                // [128, 11008]
    int use_xb) {
  // A tile: 128 rows x 64 bf16 (128B/row), XOR-swizzled: byte ^= (row&7)<<4
  // B tile: 64 cols x 64 bf16 (col-major, 128B/col), same swizzle on col
  __shared__ char aLds[BATCH * 128];
  __shared__ char bLds[BN * 128];

  const int tid  = threadIdx.x;
  const int lane = tid & 63;
  const int wid  = tid >> 6;
  const int wr   = wid >> 1;   // 0..1 : row half (64 rows)
  const int wc   = wid & 1;    // 0..1 : col half (32 cols)
  const int n0   = blockIdx.x * BN;

  f32x4 acc[4][2] = {};

  for (int chunk = 0; chunk < NCHUNK; ++chunk) {
    const int k0 = chunk * BK;
    __syncthreads();

    // ---- stage A: xb[0:128][k0:k0+64] -> aLds (swizzled) ----
#pragma unroll
    for (int i = 0; i < 4; ++i) {
      int seg = tid + 256 * i;          // 1024 segments of 16B
      int row = seg >> 3, sc = seg & 7; // 8 x 16B per row
      uint4 v;
      if (use_xb) {
        v = *(const uint4*)(xb + (size_t)row * IN_F + k0 + sc * 8);
      } else {
        const float* p = x + (size_t)row * IN_F + k0 + sc * 8;
        float4 u0 = *(const float4*)(p);
        float4 u1 = *(const float4*)(p + 4);
        v.x = f2bf_pack(u0.x, u0.y);
        v.y = f2bf_pack(u0.z, u0.w);
        v.z = f2bf_pack(u1.x, u1.y);
        v.w = f2bf_pack(u1.z, u1.w);
      }
      int off = row * 128 + ((sc * 16) ^ ((row & 7) << 4));
      *(uint4*)(aLds + off) = v;
    }

    // ---- stage B: dequant qweight[k0/8 : k0/8+8][n0:n0+64] -> bLds (swizzled) ----
    {
      int col = tid & 63;
      int g   = k0 >> 7;  // group (BK=64 divides GROUP_SIZE=128)
      float s = scales[(size_t)g * OUT_F + n0 + col];
      float z = zeros[(size_t)g * OUT_F + n0 + col];
#pragma unroll
      for (int i = 0; i < 2; ++i) {
        int qr = (tid >> 6) + 4 * i;    // packed row within chunk: 0..7
        unsigned int q = (unsigned int)qweight[(size_t)(k0 / 8 + qr) * OUT_F + n0 + col];
        float f0 = s * (float)((q >> 0)  & 0xFu) - z;
        float f1 = s * (float)((q >> 4)  & 0xFu) - z;
        float f2 = s * (float)((q >> 8)  & 0xFu) - z;
        float f3 = s * (float)((q >> 12) & 0xFu) - z;
        float f4 = s * (float)((q >> 16) & 0xFu) - z;
        float f5 = s * (float)((q >> 20) & 0xFu) - z;
        float f6 = s * (float)((q >> 24) & 0xFu) - z;
        float f7 = s * (float)((q >> 28) & 0xFu) - z;
        uint4 v;
        v.x = f2bf_pack(f0, f1);
        v.y = f2bf_pack(f2, f3);
        v.z = f2bf_pack(f4, f5);
        v.w = f2bf_pack(f6, f7);
        int off = col * 128 + ((qr * 16) ^ ((col & 7) << 4));
        *(uint4*)(bLds + off) = v;
      }
    }
    __syncthreads();

    // ---- compute: 2 k-steps of 32 ----
#pragma unroll
    for (int ks = 0; ks < 2; ++ks) {
      int kbyte = ks * 64 + ((lane >> 4) << 4);  // k = ks*32 + (lane>>4)*8, x2 bytes
      short8 bfrag[2];
#pragma unroll
      for (int ct = 0; ct < 2; ++ct) {
        int col = wc * 32 + ct * 16 + (lane & 15);
        bfrag[ct] = *(const short8*)(bLds + col * 128 + (kbyte ^ ((col & 7) << 4)));
      }
#pragma unroll
      for (int rt = 0; rt < 4; ++rt) {
        int row = wr * 64 + rt * 16 + (lane & 15);
        short8 afrag = *(const short8*)(aLds + row * 128 + (kbyte ^ ((row & 7) << 4)));
#pragma unroll
        for (int ct = 0; ct < 2; ++ct) {
          acc[rt][ct] = __builtin_amdgcn_mfma_f32_16x16x32_bf16(afrag, bfrag[ct], acc[rt][ct], 0, 0, 0);
        }
      }
    }
  }

  // ---- epilogue: C/D layout col=lane&15, row=(lane>>4)*4+reg ----
#pragma unroll
  for (int rt = 0; rt < 4; ++rt) {
#pragma unroll
    for (int ct = 0; ct < 2; ++ct) {
      int col = n0 + wc * 32 + ct * 16 + (lane & 15);
#pragma unroll
      for (int r = 0; r < 4; ++r) {
        int row = wr * 64 + rt * 16 + ((lane >> 4) << 2) + r;
        out[(size_t)row * OUT_F + col] = acc[rt][ct][r];
      }
    }
  }
}

extern "C" void kernel_launch(void* const* d_in, const int* in_sizes, int n_in,
                              void* d_out, int out_size, void* d_ws, size_t ws_size,
                              hipStream_t stream) {
  const float* x       = (const float*)d_in[0];
  const int*   qweight = (const int*)d_in[1];
  const float* scales  = (const float*)d_in[2];
  const float* zeros   = (const float*)d_in[3];
  float*       outp    = (float*)d_out;

  const size_t xb_bytes = (size_t)BATCH * IN_F * sizeof(unsigned short);  // 1 MB
  int use_xb = (ws_size >= xb_bytes) ? 1 : 0;
  unsigned short* xb = (unsigned short*)d_ws;

  if (use_xb) {
    // 128*4096 = 524288 bf16; 8 per thread -> 65536 threads -> 256 blocks
    cvt_kernel<<<256, 256, 0, stream>>>(x, (unsigned int*)d_ws);
  }
  gptq_gemm<<<OUT_F / BN, 256, 0, stream>>>(xb, x, qweight, scales, zeros, outp, use_xb);
}

// Round 3
// 42.270 us; speedup vs baseline: 3.5151x; 3.5151x over previous
//
#include <hip/hip_runtime.h>
#include <hip/hip_bf16.h>
#include <stdint.h>

// GPTQ 4-bit fused dequant + GEMM.  x[128,4096]f32 @ W[4096,11008] -> out[128,11008]f32
// W[k][n] = scales[k/128][n] * nibble(qweight[k/8][n], k%8) - zeros[k/128][n]
//
// R3: R2 (grid split-K SPLIT=4, reg-prefetch 2-phase pipeline, hoisted s/z regs)
//     + FIX: partial-mode epilogue writes to its own K-slice (outp + sl*MN).
//     R2 bug: all 4 slices raced into part[0:MN] -> 3/4 of dot product lost.

#define IN_F   4096
#define OUT_F  11008
#define BATCH  128
#define BK     64
#define BN     64
#define NCHUNK (IN_F / BK)      // 64
#define SPLIT  4
#define KSC    (NCHUNK / SPLIT) // 16 chunks per block
#define NBLK   (OUT_F / BN)     // 172
#define MN     (BATCH * OUT_F)  // 1409024

typedef __attribute__((ext_vector_type(8))) short short8;
typedef __attribute__((ext_vector_type(4))) float f32x4;

static __device__ __forceinline__ unsigned int f2bf_pack(float lo, float hi) {
  // round-to-nearest-even bf16 pair packed into one u32
  unsigned int a = __float_as_uint(lo);
  unsigned int b = __float_as_uint(hi);
  a += 0x7FFFu + ((a >> 16) & 1u);
  b += 0x7FFFu + ((b >> 16) & 1u);
  return (a >> 16) | (b & 0xFFFF0000u);
}

__global__ __launch_bounds__(256) void cvt_kernel(const float* __restrict__ x,
                                                  unsigned int* __restrict__ xb) {
  int i = blockIdx.x * 256 + threadIdx.x;   // 8 floats -> 4 u32 (8 bf16) per thread
  float4 v0 = *(const float4*)(x + (size_t)i * 8);
  float4 v1 = *(const float4*)(x + (size_t)i * 8 + 4);
  uint4 o;
  o.x = f2bf_pack(v0.x, v0.y);
  o.y = f2bf_pack(v0.z, v0.w);
  o.z = f2bf_pack(v1.x, v1.y);
  o.w = f2bf_pack(v1.z, v1.w);
  *(uint4*)(xb + (size_t)i * 4) = o;
}

__global__ __launch_bounds__(256) void zero_out(float* __restrict__ out) {
  int base = (blockIdx.x * 256 + threadIdx.x) * 16;   // 344 blocks
  float4 z = {0.f, 0.f, 0.f, 0.f};
#pragma unroll
  for (int j = 0; j < 4; ++j) *(float4*)(out + base + j * 4) = z;
}

__global__ __launch_bounds__(256) void reduce_kernel(const float* __restrict__ part,
                                                     float* __restrict__ out) {
  int base = (blockIdx.x * 256 + threadIdx.x) * 8;    // 688 blocks
  float4 s0 = {0.f, 0.f, 0.f, 0.f}, s1 = s0;
#pragma unroll
  for (int s = 0; s < SPLIT; ++s) {
    const float* p = part + (size_t)s * MN + base;
    float4 a = *(const float4*)(p);
    float4 b = *(const float4*)(p + 4);
    s0.x += a.x; s0.y += a.y; s0.z += a.z; s0.w += a.w;
    s1.x += b.x; s1.y += b.y; s1.z += b.z; s1.w += b.w;
  }
  *(float4*)(out + base)     = s0;
  *(float4*)(out + base + 4) = s1;
}

__global__ __launch_bounds__(256) void gptq_gemm(
    const unsigned short* __restrict__ xb,  // [128,4096] bf16 (may be unused)
    const float* __restrict__ x,            // [128,4096] f32 fallback
    const int* __restrict__ qweight,        // [512, 11008]
    const float* __restrict__ scales,       // [32, 11008]
    const float* __restrict__ zeros,        // [32, 11008]
    float* __restrict__ outp,               // out (atomic) or partials base
    int use_xb, int atomic_mode) {
  // A tile: 128 rows x 64 bf16 (128B/row), XOR-swizzled: byte ^= (row&7)<<4
  // B tile: 64 cols x 64 bf16 (col-major, 128B/col), same swizzle on col
  __shared__ char aLds[BATCH * 128];
  __shared__ char bLds[BN * 128];

  const int tid  = threadIdx.x;
  const int lane = tid & 63;
  const int wid  = tid >> 6;
  const int wr   = wid >> 1;   // 0..1 : row half (64 rows)
  const int wc   = wid & 1;    // 0..1 : col half (32 cols)
  const int nb   = blockIdx.x % NBLK;
  const int sl   = blockIdx.x / NBLK;
  const int n0   = nb * BN;
  const int c0   = sl * KSC;   // first chunk of this K-slice

  // FIX (R3): partial-mode blocks write to their own slice of the partials buf
  float* dst = atomic_mode ? outp : outp + (size_t)sl * MN;

  // hoist scales/zeros for the 8 groups this K-slice covers (group = 2 chunks)
  const int col = tid & 63;
  const int g0  = c0 >> 1;
  float sreg[8], zreg[8];
#pragma unroll
  for (int g = 0; g < 8; ++g) {
    sreg[g] = scales[(size_t)(g0 + g) * OUT_F + n0 + col];
    zreg[g] = zeros [(size_t)(g0 + g) * OUT_F + n0 + col];
  }

  uint4 aPre[4];
  unsigned int qPre[2];

  // ---- prologue: prefetch chunk c0 ----
  {
    const int k0 = c0 * BK;
#pragma unroll
    for (int i = 0; i < 4; ++i) {
      int seg = tid + 256 * i, row = seg >> 3, sc2 = seg & 7;
      if (use_xb) {
        aPre[i] = *(const uint4*)(xb + (size_t)row * IN_F + k0 + sc2 * 8);
      } else {
        const float* p = x + (size_t)row * IN_F + k0 + sc2 * 8;
        float4 u0 = *(const float4*)(p);
        float4 u1 = *(const float4*)(p + 4);
        aPre[i].x = f2bf_pack(u0.x, u0.y);
        aPre[i].y = f2bf_pack(u0.z, u0.w);
        aPre[i].z = f2bf_pack(u1.x, u1.y);
        aPre[i].w = f2bf_pack(u1.z, u1.w);
      }
    }
#pragma unroll
    for (int i = 0; i < 2; ++i) {
      int qr = wid + 4 * i;
      qPre[i] = (unsigned int)qweight[(size_t)(k0 / 8 + qr) * OUT_F + n0 + col];
    }
  }

  f32x4 acc[4][2] = {};

  for (int cc = 0; cc < KSC; ++cc) {
    __syncthreads();   // previous chunk's consumers done with LDS

    // ---- store prefetched A -> aLds (swizzled) ----
#pragma unroll
    for (int i = 0; i < 4; ++i) {
      int seg = tid + 256 * i, row = seg >> 3, sc2 = seg & 7;
      int off = row * 128 + ((sc2 * 16) ^ ((row & 7) << 4));
      *(uint4*)(aLds + off) = aPre[i];
    }

    // ---- dequant prefetched qweight -> bLds (swizzled) ----
    {
      float s = sreg[cc >> 1];
      float z = zreg[cc >> 1];
#pragma unroll
      for (int i = 0; i < 2; ++i) {
        unsigned int q = qPre[i];
        int qr = wid + 4 * i;
        float f0 = s * (float)((q >> 0)  & 0xFu) - z;
        float f1 = s * (float)((q >> 4)  & 0xFu) - z;
        float f2 = s * (float)((q >> 8)  & 0xFu) - z;
        float f3 = s * (float)((q >> 12) & 0xFu) - z;
        float f4 = s * (float)((q >> 16) & 0xFu) - z;
        float f5 = s * (float)((q >> 20) & 0xFu) - z;
        float f6 = s * (float)((q >> 24) & 0xFu) - z;
        float f7 = s * (float)((q >> 28) & 0xFu) - z;
        uint4 v;
        v.x = f2bf_pack(f0, f1);
        v.y = f2bf_pack(f2, f3);
        v.z = f2bf_pack(f4, f5);
        v.w = f2bf_pack(f6, f7);
        int off = col * 128 + ((qr * 16) ^ ((col & 7) << 4));
        *(uint4*)(bLds + off) = v;
      }
    }
    __syncthreads();

    // ---- prefetch chunk cc+1 (loads in flight under the MFMAs below) ----
    if (cc + 1 < KSC) {
      const int k0 = (c0 + cc + 1) * BK;
#pragma unroll
      for (int i = 0; i < 4; ++i) {
        int seg = tid + 256 * i, row = seg >> 3, sc2 = seg & 7;
        if (use_xb) {
          aPre[i] = *(const uint4*)(xb + (size_t)row * IN_F + k0 + sc2 * 8);
        } else {
          const float* p = x + (size_t)row * IN_F + k0 + sc2 * 8;
          float4 u0 = *(const float4*)(p);
          float4 u1 = *(const float4*)(p + 4);
          aPre[i].x = f2bf_pack(u0.x, u0.y);
          aPre[i].y = f2bf_pack(u0.z, u0.w);
          aPre[i].z = f2bf_pack(u1.x, u1.y);
          aPre[i].w = f2bf_pack(u1.z, u1.w);
        }
      }
#pragma unroll
      for (int i = 0; i < 2; ++i) {
        int qr = wid + 4 * i;
        qPre[i] = (unsigned int)qweight[(size_t)(k0 / 8 + qr) * OUT_F + n0 + col];
      }
    }

    // ---- compute: 2 k-steps of 32 ----
#pragma unroll
    for (int ks = 0; ks < 2; ++ks) {
      int kbyte = ks * 64 + ((lane >> 4) << 4);
      short8 bfrag[2];
#pragma unroll
      for (int ct = 0; ct < 2; ++ct) {
        int c = wc * 32 + ct * 16 + (lane & 15);
        bfrag[ct] = *(const short8*)(bLds + c * 128 + (kbyte ^ ((c & 7) << 4)));
      }
#pragma unroll
      for (int rt = 0; rt < 4; ++rt) {
        int row = wr * 64 + rt * 16 + (lane & 15);
        short8 afrag = *(const short8*)(aLds + row * 128 + (kbyte ^ ((row & 7) << 4)));
#pragma unroll
        for (int ct = 0; ct < 2; ++ct) {
          acc[rt][ct] = __builtin_amdgcn_mfma_f32_16x16x32_bf16(afrag, bfrag[ct], acc[rt][ct], 0, 0, 0);
        }
      }
    }
  }

  // ---- epilogue: C/D layout col=lane&15, row=(lane>>4)*4+reg ----
#pragma unroll
  for (int rt = 0; rt < 4; ++rt) {
#pragma unroll
    for (int ct = 0; ct < 2; ++ct) {
      int c = n0 + wc * 32 + ct * 16 + (lane & 15);
#pragma unroll
      for (int r = 0; r < 4; ++r) {
        int row = wr * 64 + rt * 16 + ((lane >> 4) << 2) + r;
        if (atomic_mode) {
          atomicAdd(dst + (size_t)row * OUT_F + c, acc[rt][ct][r]);
        } else {
          dst[(size_t)row * OUT_F + c] = acc[rt][ct][r];
        }
      }
    }
  }
}

extern "C" void kernel_launch(void* const* d_in, const int* in_sizes, int n_in,
                              void* d_out, int out_size, void* d_ws, size_t ws_size,
                              hipStream_t stream) {
  const float* x       = (const float*)d_in[0];
  const int*   qweight = (const int*)d_in[1];
  const float* scales  = (const float*)d_in[2];
  const float* zeros   = (const float*)d_in[3];
  float*       outp    = (float*)d_out;

  const size_t xb_bytes   = (size_t)BATCH * IN_F * sizeof(unsigned short);  // 1 MB
  const size_t part_bytes = (size_t)SPLIT * MN * sizeof(float);             // 22.5 MB
  int use_xb   = (ws_size >= xb_bytes) ? 1 : 0;
  int partials = (ws_size >= xb_bytes + part_bytes) ? 1 : 0;

  unsigned short* xb   = (unsigned short*)d_ws;
  float*          part = (float*)((char*)d_ws + xb_bytes);

  if (use_xb) {
    cvt_kernel<<<256, 256, 0, stream>>>(x, (unsigned int*)d_ws);
  }

  if (partials) {
    gptq_gemm<<<NBLK * SPLIT, 256, 0, stream>>>(xb, x, qweight, scales, zeros,
                                                part, use_xb, 0);
    reduce_kernel<<<688, 256, 0, stream>>>(part, outp);
  } else {
    zero_out<<<344, 256, 0, stream>>>(outp);
    gptq_gemm<<<NBLK * SPLIT, 256, 0, stream>>>(xb, x, qweight, scales, zeros,
                                                outp, use_xb, 1);
  }
}